// Round 11
// baseline (318.192 us; speedup 1.0000x reference)
//
#include <hip/hip_runtime.h>
#include <hip/hip_bf16.h>
#include <math.h>

#define PDIM 2198
#define PDIM2 2252          // PDIM + 54-col zero halo (wrap-free staging in x)
#define PADB 75
#define NANG 32
#define NLINE (NANG * PDIM) // 70336

// radon geometry
#define CB 32      // c-values per block
#define RW 32      // r-values per window
#define NWIN 69    // ceil(2198/32)
#define TS 48      // staged box rows (span proof: <=47 used)
#define TSTRIDE 52 // staged cols per row; multiple of 4 for 16B staging
#define NBUF 3     // ring; stage(w+2) issued AFTER barrier -> mod-3 safe

typedef __attribute__((ext_vector_type(8))) short bf16x8;
typedef __attribute__((ext_vector_type(4))) float f32x4;

template<bool L> struct BoolC { static constexpr bool value = L; };

#define GLOAD_LDS16(g, l)                                              \
    __builtin_amdgcn_global_load_lds(                                  \
        (const __attribute__((address_space(1))) void*)(g),            \
        (__attribute__((address_space(3))) void*)(l), 16, 0, 0)

#if __has_builtin(__builtin_amdgcn_fractf)
#define FRACTF(x) __builtin_amdgcn_fractf(x)
#else
#define FRACTF(x) ((x) - floorf(x))
#endif

// ---------------------------------------------------------------- DCT matrix (bf16)
__global__ void gen_dct(__hip_bfloat16* __restrict__ C) {
    int idx = blockIdx.x * 256 + threadIdx.x;
    int k = idx >> 11;
    int n = idx & 2047;
    int t = ((2 * n + 1) * k) & 8191;
    float s = sqrtf(((k == 0) ? 1.0f : 2.0f) / 2048.0f);
    C[idx] = __float2bfloat16(s * cospif((float)t * (1.0f / 4096.0f)));
}

// ---------------------------------------------------------------- img fp32 -> bf16
__global__ void cvt_img(const float* __restrict__ in, __hip_bfloat16* __restrict__ out) {
    int i = (blockIdx.x * 256 + threadIdx.x) * 4;
    float4 v = *(const float4*)(in + i);
    out[i + 0] = __float2bfloat16(v.x);
    out[i + 1] = __float2bfloat16(v.y);
    out[i + 2] = __float2bfloat16(v.z);
    out[i + 3] = __float2bfloat16(v.w);
}

// ---------------------------------------------------------------- zero pad borders
__global__ __launch_bounds__(256) void pad_zero(float* __restrict__ padded) {
    int idx = blockIdx.x * 256 + threadIdx.x;
    const int TOPBOT = 2 * PADB * PDIM2;            // 337800
    if (idx < TOPBOT) {
        int r = idx / PDIM2;
        int c = idx - r * PDIM2;
        int row = (r < PADB) ? r : (2048 + r);      // 0..74 / 2123..2197
        padded[(size_t)row * PDIM2 + c] = 0.0f;
    } else {
        int i2 = idx - TOPBOT;
        if (i2 >= 2048 * 204) return;
        int rr = i2 / 204;
        int s = i2 - rr * 204;
        int col = (s < PADB) ? s : (2048 + s);      // 0..74 / 2123..2251
        padded[(size_t)(PADB + rr) * PDIM2 + col] = 0.0f;
    }
}

// ---------------------------------------------------------------- pack f32 -> bf16 pairs
// imgP[y][x] = (bf16 v[y][x]) | (bf16 v[y][x+1]) << 16. One u32 per pixel: a
// bilinear sample's row pair (v[x], v[x+1]) is ONE dword -> one ds_read2_b32
// for both rows in the radon kernel (4 ds_read_b32 -> 1 instruction).
__global__ __launch_bounds__(256) void pack_img(const float* __restrict__ padded,
                                                unsigned* __restrict__ imgP) {
    const int W4 = PDIM2 / 4;                       // 563
    int idx = blockIdx.x * 256 + threadIdx.x;
    int y = idx / W4;
    if (y >= PDIM) return;
    int x4 = (idx - y * W4) * 4;
    const float* row = padded + (size_t)y * PDIM2;
    float4 v = *(const float4*)(row + x4);
    float v4 = (x4 + 4 < PDIM2) ? row[x4 + 4] : 0.0f;  // col 2251's hi: never sampled
    __hip_bfloat162 p0 = __float22bfloat162_rn(make_float2(v.x, v.y));
    __hip_bfloat162 p1 = __float22bfloat162_rn(make_float2(v.y, v.z));
    __hip_bfloat162 p2 = __float22bfloat162_rn(make_float2(v.z, v.w));
    __hip_bfloat162 p3 = __float22bfloat162_rn(make_float2(v.w, v4));
    uint4 o;
    o.x = *(unsigned*)&p0; o.y = *(unsigned*)&p1;
    o.z = *(unsigned*)&p2; o.w = *(unsigned*)&p3;
    *(uint4*)(imgP + (size_t)y * PDIM2 + x4) = o;
}

// ---------------------------------------------------------------- MFMA GEMM (B^T form)
// D[row][col] = sum_k A[row][k]*B[col][k]; output stored TRANSPOSED out[col][row].
// 128x64 tile, BK=32, 256 thr = 4 waves; grid (32,16)=512 blocks = 2/CU.
template<int F32OUT>
__global__ __launch_bounds__(256) void gemm_bt(const __hip_bfloat16* __restrict__ A,
                                               const __hip_bfloat16* __restrict__ B,
                                               void* __restrict__ out,
                                               int ldo, int off) {
    __shared__ __hip_bfloat16 Al[128 * 32];
    __shared__ __hip_bfloat16 Bl[64 * 32];
    const int tid = threadIdx.x;
    const int wid = tid >> 6;
    const int lane = tid & 63;
    const int wr = wid >> 1, wc = wid & 1;
    const int l15 = lane & 15, lhi = lane >> 4;
    const int row0 = blockIdx.y * 128;
    const int col0 = blockIdx.x * 64;

    const __hip_bfloat16* gA = A + (size_t)(row0 + wid * 32 + (lane >> 2)) * 2048 + (lane & 3) * 8;
    const __hip_bfloat16* gB = B + (size_t)(col0 + wid * 16 + (lane >> 2)) * 2048 + (lane & 3) * 8;
    __hip_bfloat16* lA = Al + wid * 1024;
    __hip_bfloat16* lB = Bl + wid * 512;

    f32x4 acc[4][2] = {};

    for (int k0 = 0; k0 < 2048; k0 += 32) {
        GLOAD_LDS16(gA + k0, lA);
        GLOAD_LDS16(gA + 16 * 2048 + k0, lA + 16 * 32);
        GLOAD_LDS16(gB + k0, lB);
        __syncthreads();
        bf16x8 af[4], bfr[2];
#pragma unroll
        for (int m = 0; m < 4; ++m)
            af[m] = *(const bf16x8*)(Al + (wr * 64 + m * 16 + l15) * 32 + lhi * 8);
#pragma unroll
        for (int n = 0; n < 2; ++n)
            bfr[n] = *(const bf16x8*)(Bl + (wc * 32 + n * 16 + l15) * 32 + lhi * 8);
#pragma unroll
        for (int m = 0; m < 4; ++m)
#pragma unroll
            for (int n = 0; n < 2; ++n)
                acc[m][n] = __builtin_amdgcn_mfma_f32_16x16x32_bf16(af[m], bfr[n],
                                                                    acc[m][n], 0, 0, 0);
        __syncthreads();
    }

#pragma unroll
    for (int m = 0; m < 4; ++m) {
        const int row = row0 + wr * 64 + m * 16 + lhi * 4;
#pragma unroll
        for (int n = 0; n < 2; ++n) {
            const int col = col0 + wc * 32 + n * 16 + l15;
            f32x4 v = acc[m][n];
            if (F32OUT) {
                float* p = (float*)out + (size_t)(col + off) * ldo + off + row;
                p[0] = v[0]; p[1] = v[1]; p[2] = v[2]; p[3] = v[3];
            } else {
                __hip_bfloat16* p = (__hip_bfloat16*)out + (size_t)col * 2048 + row;
                p[0] = __float2bfloat16(v[0]);
                p[1] = __float2bfloat16(v[1]);
                p[2] = __float2bfloat16(v[2]);
                p[3] = __float2bfloat16(v[3]);
            }
        }
    }
}

// ---------------------------------------------------------------- radon
struct AngleArgs {
    float ca[NANG], sa[NANG], ox[NANG], oy[NANG];
};

// grid: (69 c-blocks, 32 angles), 256 threads = 4 waves, 8x8 (c,r) lane tile.
// Tile holds packed bf16 pairs: one sample = dwords idx and idx+TSTRIDE
// (same base, imm offsets 0/52 -> ds_read2_b32). Unpack via <<16 / &hi16.
__global__ __launch_bounds__(256) void radon8(const unsigned* __restrict__ imgP,
                                              float* __restrict__ lines,
                                              AngleArgs args) {
    __shared__ unsigned tile[NBUF][TS * TSTRIDE];
    __shared__ float red[4][8];
    const int a = blockIdx.y;
    const int c0 = blockIdx.x * CB;
    const int t = threadIdx.x;
    const int wid = t >> 6, lane = t & 63;
    const int cl = lane >> 3;
    const int rl = lane & 7;
    const int c = c0 + wid * 8 + cl;
    const float ca = args.ca[a], sa = args.sa[a];   // sa >= 0 for theta in [0,pi]
    const float ox = args.ox[a], oy = args.oy[a];

    const float cf = (float)c;
    const float xbase = fmaf(ca, cf, ox);    // + sa*r
    const float ybase = fmaf(-sa, cf, oy);   // + ca*r

    const float xbMin = fminf(fmaf(ca, (float)c0, ox), fmaf(ca, (float)(c0 + CB - 1), ox));
    const float ybMin = fminf(fmaf(-sa, (float)c0, oy), fmaf(-sa, (float)(c0 + CB - 1), oy));
    const bool caPos = (ca >= 0.0f);

    float sum = 0.0f;

    auto origin = [&](int w, int& bx0, int& by0) {
        const float rx = (float)(w * RW);
        const float ry = caPos ? rx : (float)(w * RW + RW - 1);
        bx0 = (int)floorf(fmaf(sa, rx, xbMin)) - 1;
        by0 = (int)floorf(fmaf(ca, ry, ybMin)) - 1;
    };

    auto stage = [&](int buf, int bx0, int by0) {
        int bxs = bx0;
        bxs += (bxs < 0) ? PDIM : 0;
        bxs -= (bxs >= PDIM) ? PDIM : 0;     // [0,2197]; +51 <= 2248 < PDIM2
        const int slab = wid * 12;
#pragma unroll
        for (int iss = 0; iss < 3; ++iss) {
            const int d = iss * 256 + lane * 4;
            if (d < 12 * TSTRIDE) {
                const int rr = d / TSTRIDE;
                const int col = d - rr * TSTRIDE;
                int gy = by0 + slab + rr;
                gy += (gy < 0) ? PDIM : 0;
                gy -= (gy >= PDIM) ? PDIM : 0;
                GLOAD_LDS16(imgP + (size_t)gy * PDIM2 + bxs + col,
                            &tile[buf][slab * TSTRIDE + iss * 256]);
            }
        }
    };

    auto computeT = [&](int r0, int buf, int bx0, int by0, auto lastc) {
        const float xbb = xbase - (float)bx0;   // exact f32 sub
        const float ybb = ybase - (float)by0;
        const unsigned* tb = &tile[buf][0];
#pragma unroll
        for (int k = 0; k < 4; ++k) {
            const int r = r0 + rl + 8 * k;
            const float rf = (float)r;
            const float xl = fmaf(sa, rf, xbb);
            const float yl = fmaf(ca, rf, ybb);
            const int xi = (int)xl;
            const int yi = (int)yl;
            const float wx = FRACTF(xl);
            const float wy = FRACTF(yl);
            const int idx = yi * TSTRIDE + xi;
            const unsigned u0 = tb[idx];             // merges to ds_read2_b32
            const unsigned u1 = tb[idx + TSTRIDE];
            const float v00 = __uint_as_float(u0 << 16);
            const float v01 = __uint_as_float(u0 & 0xffff0000u);
            const float v10 = __uint_as_float(u1 << 16);
            const float v11 = __uint_as_float(u1 & 0xffff0000u);
            const float top = fmaf(wx, v01 - v00, v00);
            const float bot = fmaf(wx, v11 - v10, v10);
            if (!decltype(lastc)::value || r < PDIM) sum = fmaf(wy, bot - top, sum + top);
        }
    };

    int bxr[3], byr[3];
    origin(0, bxr[0], byr[0]);
    stage(0, bxr[0], byr[0]);
    origin(1, bxr[1], byr[1]);
    stage(1, bxr[1], byr[1]);
    for (int w = 0; w < NWIN; ++w) {
        // outstanding here: stage(w) [maybe], stage(w+1) [if exists]
        if (w < NWIN - 1) asm volatile("s_waitcnt vmcnt(3)" ::: "memory");
        else              asm volatile("s_waitcnt vmcnt(0)" ::: "memory");
        __builtin_amdgcn_s_barrier();           // orders compute(w-1) before stage(w+2)
        __builtin_amdgcn_sched_barrier(0);
        if (w + 2 < NWIN) {
            const int wn = (w + 2) % 3;
            origin(w + 2, bxr[wn], byr[wn]);
            stage(wn, bxr[wn], byr[wn]);        // latency hides under compute(w), compute(w+1)
        }
        const int wi = w % 3;
        if (w < NWIN - 1) computeT(w * RW, wi, bxr[wi], byr[wi], BoolC<false>{});
        else              computeT(w * RW, wi, bxr[wi], byr[wi], BoolC<true>{});
    }

    sum += __shfl_xor(sum, 1, 64);
    sum += __shfl_xor(sum, 2, 64);
    sum += __shfl_xor(sum, 4, 64);
    if (rl == 0) red[wid][cl] = sum;
    __syncthreads();
    if (t < 32 && c0 + t < PDIM)
        lines[a * PDIM + c0 + t] = red[t >> 3][t & 7];
}

// ---------------------------------------------------------------- max
__global__ __launch_bounds__(256) void max_k(const float* __restrict__ lines,
                                             unsigned int* __restrict__ gmax) {
    const int idx = blockIdx.x * 256 + threadIdx.x;
    float m = (idx < NLINE) ? lines[idx] : -3.4e38f;
#pragma unroll
    for (int off = 32; off > 0; off >>= 1)
        m = fmaxf(m, __shfl_down(m, off, 64));
    __shared__ float wm[4];
    const int lane = threadIdx.x & 63, wid = threadIdx.x >> 6;
    if (lane == 0) wm[wid] = m;
    __syncthreads();
    if (threadIdx.x == 0) {
        float bm = fmaxf(fmaxf(wm[0], wm[1]), fmaxf(wm[2], wm[3]));
        unsigned int b = __float_as_uint(bm);
        unsigned int key = (b & 0x80000000u) ? ~b : (b | 0x80000000u);
        atomicMax(gmax, key);
    }
}

// ---------------------------------------------------------------- normalize
__global__ void norm_k(const float* __restrict__ lines,
                       const unsigned int* __restrict__ gmax,
                       float* __restrict__ out) {
    int idx = blockIdx.x * 256 + threadIdx.x;
    if (idx >= NLINE) return;
    unsigned int u = *gmax;
    unsigned int b = (u & 0x80000000u) ? (u & 0x7fffffffu) : ~u;
    float mx = __uint_as_float(b);
    int c = idx >> 5;
    int a = idx & 31;
    out[idx] = lines[(size_t)a * PDIM + c] / mx;
}

// ---------------------------------------------------------------- launch
extern "C" void kernel_launch(void* const* d_in, const int* in_sizes, int n_in,
                              void* d_out, int out_size, void* d_ws, size_t ws_size,
                              hipStream_t stream) {
    (void)in_sizes; (void)n_in; (void)out_size; (void)ws_size;
    const float* img = (const float*)d_in[0];
    float* out = (float*)d_out;

    // Phase-1 buffers (dead after gemm2) share bytes [0,24MB) with imgP.
    __hip_bfloat16* Cbf   = (__hip_bfloat16*)d_ws;      // [0,8M)
    __hip_bfloat16* imgbf = Cbf + 4194304;              // [8M,16M)
    __hip_bfloat16* uT    = imgbf + 4194304;            // [16M,24M)
    unsigned* imgP = (unsigned*)d_ws;                   // [0,19.8M)  phase 2
    float* padded  = (float*)(uT + 4194304);            // [24M, 43.8M)
    float* lines   = padded + (size_t)PDIM * PDIM2;
    unsigned int* gmax = (unsigned int*)(lines + NLINE);

    (void)hipMemsetAsync(gmax, 0, sizeof(unsigned int), stream);

    gen_dct<<<16384, 256, 0, stream>>>(Cbf);
    cvt_img<<<4096, 256, 0, stream>>>(img, imgbf);
    pad_zero<<<(2 * PADB * PDIM2 + 2048 * 204 + 255) / 256, 256, 0, stream>>>(padded);

    gemm_bt<0><<<dim3(32, 16), 256, 0, stream>>>(imgbf, Cbf, uT, 2048, 0);
    gemm_bt<1><<<dim3(32, 16), 256, 0, stream>>>(uT, Cbf, padded, PDIM2, PADB);

    pack_img<<<(PDIM * (PDIM2 / 4) + 255) / 256, 256, 0, stream>>>(padded, imgP);

    AngleArgs aa;
    for (int i = 0; i < NANG; ++i) {
        float th = (float)((double)i * 3.14159265358979323846 / 31.0);
        float ca = (float)cos((double)th);
        float sa = (float)sin((double)th);
        aa.ca[i] = ca;
        aa.sa[i] = sa;
        aa.ox[i] = -1099.0f * (ca + sa - 1.0f);
        aa.oy[i] = -1099.0f * (ca - sa - 1.0f);
    }
    radon8<<<dim3(NWIN, NANG), 256, 0, stream>>>(imgP, lines, aa);
    max_k<<<(NLINE + 255) / 256, 256, 0, stream>>>(lines, gmax);
    norm_k<<<(NLINE + 255) / 256, 256, 0, stream>>>(lines, gmax, out);
}

// Round 12
// 314.765 us; speedup vs baseline: 1.0109x; 1.0109x over previous
//
#include <hip/hip_runtime.h>
#include <hip/hip_bf16.h>
#include <math.h>

#define PDIM 2198
#define PDIM2 2252          // PDIM + 54-col zero halo (wrap-free staging in x)
#define PADB 75
#define NANG 32
#define NLINE (NANG * PDIM) // 70336

// radon geometry
#define CB 32      // c-values per block
#define RW 32      // r-values per window
#define NWIN 69    // ceil(2198/32)
#define WSPLIT 35  // rc=0: windows [0,35); rc=1: [35,69)
#define TS 48      // staged box rows (span proof: <=47 used)
#define TSTRIDE 52 // staged cols per row; multiple of 4 for 16B staging
#define NBUF 3     // ring; stage(w+2) issued AFTER barrier -> mod-3 safe

typedef __attribute__((ext_vector_type(8))) short bf16x8;
typedef __attribute__((ext_vector_type(4))) float f32x4;

template<bool L> struct BoolC { static constexpr bool value = L; };

#define GLOAD_LDS16(g, l)                                              \
    __builtin_amdgcn_global_load_lds(                                  \
        (const __attribute__((address_space(1))) void*)(g),            \
        (__attribute__((address_space(3))) void*)(l), 16, 0, 0)

#if __has_builtin(__builtin_amdgcn_fractf)
#define FRACTF(x) __builtin_amdgcn_fractf(x)
#else
#define FRACTF(x) ((x) - floorf(x))
#endif

// ---------------------------------------------------------------- DCT matrix (bf16)
__global__ void gen_dct(__hip_bfloat16* __restrict__ C) {
    int idx = blockIdx.x * 256 + threadIdx.x;
    int k = idx >> 11;
    int n = idx & 2047;
    int t = ((2 * n + 1) * k) & 8191;
    float s = sqrtf(((k == 0) ? 1.0f : 2.0f) / 2048.0f);
    C[idx] = __float2bfloat16(s * cospif((float)t * (1.0f / 4096.0f)));
}

// ---------------------------------------------------------------- img fp32 -> bf16
__global__ void cvt_img(const float* __restrict__ in, __hip_bfloat16* __restrict__ out) {
    int i = (blockIdx.x * 256 + threadIdx.x) * 4;
    float4 v = *(const float4*)(in + i);
    out[i + 0] = __float2bfloat16(v.x);
    out[i + 1] = __float2bfloat16(v.y);
    out[i + 2] = __float2bfloat16(v.z);
    out[i + 3] = __float2bfloat16(v.w);
}

// ---------------------------------------------------------------- zero pad borders
__global__ __launch_bounds__(256) void pad_zero(float* __restrict__ padded) {
    int idx = blockIdx.x * 256 + threadIdx.x;
    const int TOPBOT = 2 * PADB * PDIM2;            // 337800
    if (idx < TOPBOT) {
        int r = idx / PDIM2;
        int c = idx - r * PDIM2;
        int row = (r < PADB) ? r : (2048 + r);      // 0..74 / 2123..2197
        padded[(size_t)row * PDIM2 + c] = 0.0f;
    } else {
        int i2 = idx - TOPBOT;
        if (i2 >= 2048 * 204) return;
        int rr = i2 / 204;
        int s = i2 - rr * 204;
        int col = (s < PADB) ? s : (2048 + s);      // 0..74 / 2123..2251
        padded[(size_t)(PADB + rr) * PDIM2 + col] = 0.0f;
    }
}

// ---------------------------------------------------------------- MFMA GEMM (B^T form)
// D[row][col] = sum_k A[row][k]*B[col][k]; output stored TRANSPOSED out[col][row].
// 128x64 tile, BK=32, 256 thr = 4 waves; grid (32,16)=512 blocks = 2/CU.
template<int F32OUT>
__global__ __launch_bounds__(256) void gemm_bt(const __hip_bfloat16* __restrict__ A,
                                               const __hip_bfloat16* __restrict__ B,
                                               void* __restrict__ out,
                                               int ldo, int off) {
    __shared__ __hip_bfloat16 Al[128 * 32];
    __shared__ __hip_bfloat16 Bl[64 * 32];
    const int tid = threadIdx.x;
    const int wid = tid >> 6;
    const int lane = tid & 63;
    const int wr = wid >> 1, wc = wid & 1;
    const int l15 = lane & 15, lhi = lane >> 4;
    const int row0 = blockIdx.y * 128;
    const int col0 = blockIdx.x * 64;

    const __hip_bfloat16* gA = A + (size_t)(row0 + wid * 32 + (lane >> 2)) * 2048 + (lane & 3) * 8;
    const __hip_bfloat16* gB = B + (size_t)(col0 + wid * 16 + (lane >> 2)) * 2048 + (lane & 3) * 8;
    __hip_bfloat16* lA = Al + wid * 1024;
    __hip_bfloat16* lB = Bl + wid * 512;

    f32x4 acc[4][2] = {};

    for (int k0 = 0; k0 < 2048; k0 += 32) {
        GLOAD_LDS16(gA + k0, lA);
        GLOAD_LDS16(gA + 16 * 2048 + k0, lA + 16 * 32);
        GLOAD_LDS16(gB + k0, lB);
        __syncthreads();
        bf16x8 af[4], bfr[2];
#pragma unroll
        for (int m = 0; m < 4; ++m)
            af[m] = *(const bf16x8*)(Al + (wr * 64 + m * 16 + l15) * 32 + lhi * 8);
#pragma unroll
        for (int n = 0; n < 2; ++n)
            bfr[n] = *(const bf16x8*)(Bl + (wc * 32 + n * 16 + l15) * 32 + lhi * 8);
#pragma unroll
        for (int m = 0; m < 4; ++m)
#pragma unroll
            for (int n = 0; n < 2; ++n)
                acc[m][n] = __builtin_amdgcn_mfma_f32_16x16x32_bf16(af[m], bfr[n],
                                                                    acc[m][n], 0, 0, 0);
        __syncthreads();
    }

#pragma unroll
    for (int m = 0; m < 4; ++m) {
        const int row = row0 + wr * 64 + m * 16 + lhi * 4;
#pragma unroll
        for (int n = 0; n < 2; ++n) {
            const int col = col0 + wc * 32 + n * 16 + l15;
            f32x4 v = acc[m][n];
            if (F32OUT) {
                float* p = (float*)out + (size_t)(col + off) * ldo + off + row;
                p[0] = v[0]; p[1] = v[1]; p[2] = v[2]; p[3] = v[3];
            } else {
                __hip_bfloat16* p = (__hip_bfloat16*)out + (size_t)col * 2048 + row;
                p[0] = __float2bfloat16(v[0]);
                p[1] = __float2bfloat16(v[1]);
                p[2] = __float2bfloat16(v[2]);
                p[3] = __float2bfloat16(v[3]);
            }
        }
    }
}

// ---------------------------------------------------------------- radon
struct AngleArgs {
    float ca[NANG], sa[NANG], ox[NANG], oy[NANG];
};

// Flattened 1-D grid of 4416 blocks with XCD-chunked work decode:
//   xcd = lid & 7, g = lid >> 3 (0..551)
//   angle = xcd + 8*(g/138); rem = g%138; rc = rem/69; cblk = rem%69
// => each XCD (heuristic: lid%8) runs consecutive c-blocks of one angle, so
// co-resident blocks share ~55%-overlapping 48-wide bands -> L2 hits.
// Bijective for any xcd heuristic, so correctness never depends on it.
// rc splits the 69 windows 35/34; partials summed in reduce_max_k.
__global__ __launch_bounds__(256) void radon9(const float* __restrict__ padded,
                                              float* __restrict__ lines2,
                                              AngleArgs args) {
    __shared__ float tile[NBUF][TS * TSTRIDE];
    __shared__ float red[4][8];
    const int lid = blockIdx.x;
    const int g = lid >> 3;
    const int a = (lid & 7) + 8 * (g / 138);
    const int rem = g % 138;
    const int rc = rem / 69;
    const int c0 = (rem % 69) * CB;
    const int wbeg = rc ? WSPLIT : 0;
    const int wend = rc ? NWIN : WSPLIT;

    const int t = threadIdx.x;
    const int wid = t >> 6, lane = t & 63;
    const int cl = lane >> 3;
    const int rl = lane & 7;
    const int c = c0 + wid * 8 + cl;
    const float ca = args.ca[a], sa = args.sa[a];   // sa >= 0 for theta in [0,pi]
    const float ox = args.ox[a], oy = args.oy[a];

    const float cf = (float)c;
    const float xbase = fmaf(ca, cf, ox);    // + sa*r
    const float ybase = fmaf(-sa, cf, oy);   // + ca*r

    const float xbMin = fminf(fmaf(ca, (float)c0, ox), fmaf(ca, (float)(c0 + CB - 1), ox));
    const float ybMin = fminf(fmaf(-sa, (float)c0, oy), fmaf(-sa, (float)(c0 + CB - 1), oy));
    const bool caPos = (ca >= 0.0f);

    float sum = 0.0f;

    auto origin = [&](int w, int& bx0, int& by0) {
        const float rx = (float)(w * RW);
        const float ry = caPos ? rx : (float)(w * RW + RW - 1);
        bx0 = (int)floorf(fmaf(sa, rx, xbMin)) - 1;
        by0 = (int)floorf(fmaf(ca, ry, ybMin)) - 1;
    };

    auto stage = [&](int buf, int bx0, int by0) {
        int bxs = bx0;
        bxs += (bxs < 0) ? PDIM : 0;
        bxs -= (bxs >= PDIM) ? PDIM : 0;     // [0,2197]; +51 <= 2248 < PDIM2
        const int slab = wid * 12;
#pragma unroll
        for (int iss = 0; iss < 3; ++iss) {
            const int d = iss * 256 + lane * 4;
            if (d < 12 * TSTRIDE) {
                const int rr = d / TSTRIDE;
                const int col = d - rr * TSTRIDE;
                int gy = by0 + slab + rr;
                gy += (gy < 0) ? PDIM : 0;
                gy -= (gy >= PDIM) ? PDIM : 0;
                GLOAD_LDS16(padded + (size_t)gy * PDIM2 + bxs + col,
                            &tile[buf][slab * TSTRIDE + iss * 256]);
            }
        }
    };

    auto computeT = [&](int r0, int buf, int bx0, int by0, auto lastc) {
        const float xbb = xbase - (float)bx0;   // exact f32 sub
        const float ybb = ybase - (float)by0;
        const float* tb = &tile[buf][0];
#pragma unroll
        for (int k = 0; k < 4; ++k) {
            const int r = r0 + rl + 8 * k;
            const float rf = (float)r;
            const float xl = fmaf(sa, rf, xbb);
            const float yl = fmaf(ca, rf, ybb);
            const int xi = (int)xl;
            const int yi = (int)yl;
            const float wx = FRACTF(xl);
            const float wy = FRACTF(yl);
            const float* p = tb + yi * TSTRIDE + xi;
            const float v00 = p[0], v01 = p[1];
            const float v10 = p[TSTRIDE], v11 = p[TSTRIDE + 1];
            const float top = fmaf(wx, v01 - v00, v00);
            const float bot = fmaf(wx, v11 - v10, v10);
            if (!decltype(lastc)::value || r < PDIM) sum = fmaf(wy, bot - top, sum + top);
        }
    };

    int bxr[3], byr[3];
    origin(wbeg, bxr[wbeg % 3], byr[wbeg % 3]);
    stage(wbeg % 3, bxr[wbeg % 3], byr[wbeg % 3]);
    origin(wbeg + 1, bxr[(wbeg + 1) % 3], byr[(wbeg + 1) % 3]);
    stage((wbeg + 1) % 3, bxr[(wbeg + 1) % 3], byr[(wbeg + 1) % 3]);
    for (int w = wbeg; w < wend; ++w) {
        // outstanding here: stage(w) [maybe], stage(w+1) [if exists]
        if (w < wend - 1) asm volatile("s_waitcnt vmcnt(3)" ::: "memory");
        else              asm volatile("s_waitcnt vmcnt(0)" ::: "memory");
        __builtin_amdgcn_s_barrier();           // orders compute(w-1) before stage(w+2)
        __builtin_amdgcn_sched_barrier(0);
        if (w + 2 < wend) {
            const int wn = (w + 2) % 3;
            origin(w + 2, bxr[wn], byr[wn]);
            stage(wn, bxr[wn], byr[wn]);        // latency hides under compute(w), compute(w+1)
        }
        const int wi = w % 3;
        if (w < NWIN - 1) computeT(w * RW, wi, bxr[wi], byr[wi], BoolC<false>{});
        else              computeT(w * RW, wi, bxr[wi], byr[wi], BoolC<true>{});
    }

    sum += __shfl_xor(sum, 1, 64);
    sum += __shfl_xor(sum, 2, 64);
    sum += __shfl_xor(sum, 4, 64);
    if (rl == 0) red[wid][cl] = sum;
    __syncthreads();
    if (t < 32 && c0 + t < PDIM)
        lines2[(size_t)rc * NLINE + a * PDIM + c0 + t] = red[t >> 3][t & 7];
}

// ---------------------------------------------------------------- reduce partials + max
__global__ __launch_bounds__(256) void reduce_max_k(const float* __restrict__ lines2,
                                                    float* __restrict__ lines,
                                                    unsigned int* __restrict__ gmax) {
    const int idx = blockIdx.x * 256 + threadIdx.x;
    float s = -3.4e38f;
    if (idx < NLINE) {
        s = lines2[idx] + lines2[NLINE + idx];
        lines[idx] = s;
    }
    float m = s;
#pragma unroll
    for (int off = 32; off > 0; off >>= 1)
        m = fmaxf(m, __shfl_down(m, off, 64));
    __shared__ float wm[4];
    const int lane = threadIdx.x & 63, wid = threadIdx.x >> 6;
    if (lane == 0) wm[wid] = m;
    __syncthreads();
    if (threadIdx.x == 0) {
        float bm = fmaxf(fmaxf(wm[0], wm[1]), fmaxf(wm[2], wm[3]));
        unsigned int b = __float_as_uint(bm);
        unsigned int key = (b & 0x80000000u) ? ~b : (b | 0x80000000u);
        atomicMax(gmax, key);
    }
}

// ---------------------------------------------------------------- normalize
__global__ void norm_k(const float* __restrict__ lines,
                       const unsigned int* __restrict__ gmax,
                       float* __restrict__ out) {
    int idx = blockIdx.x * 256 + threadIdx.x;
    if (idx >= NLINE) return;
    unsigned int u = *gmax;
    unsigned int b = (u & 0x80000000u) ? (u & 0x7fffffffu) : ~u;
    float mx = __uint_as_float(b);
    int c = idx >> 5;
    int a = idx & 31;
    out[idx] = lines[(size_t)a * PDIM + c] / mx;
}

// ---------------------------------------------------------------- launch
extern "C" void kernel_launch(void* const* d_in, const int* in_sizes, int n_in,
                              void* d_out, int out_size, void* d_ws, size_t ws_size,
                              hipStream_t stream) {
    (void)in_sizes; (void)n_in; (void)out_size; (void)ws_size;
    const float* img = (const float*)d_in[0];
    float* out = (float*)d_out;

    __hip_bfloat16* Cbf   = (__hip_bfloat16*)d_ws;      // [0,8M)
    __hip_bfloat16* imgbf = Cbf + 4194304;              // [8M,16M)
    __hip_bfloat16* uT    = imgbf + 4194304;            // [16M,24M)
    float* padded  = (float*)(uT + 4194304);            // [24M, 43.8M)
    float* lines2  = padded + (size_t)PDIM * PDIM2;     // 2*NLINE
    float* lines   = lines2 + 2 * (size_t)NLINE;        // NLINE
    unsigned int* gmax = (unsigned int*)(lines + NLINE);

    (void)hipMemsetAsync(gmax, 0, sizeof(unsigned int), stream);

    gen_dct<<<16384, 256, 0, stream>>>(Cbf);
    cvt_img<<<4096, 256, 0, stream>>>(img, imgbf);
    pad_zero<<<(2 * PADB * PDIM2 + 2048 * 204 + 255) / 256, 256, 0, stream>>>(padded);

    gemm_bt<0><<<dim3(32, 16), 256, 0, stream>>>(imgbf, Cbf, uT, 2048, 0);
    gemm_bt<1><<<dim3(32, 16), 256, 0, stream>>>(uT, Cbf, padded, PDIM2, PADB);

    AngleArgs aa;
    for (int i = 0; i < NANG; ++i) {
        float th = (float)((double)i * 3.14159265358979323846 / 31.0);
        float ca = (float)cos((double)th);
        float sa = (float)sin((double)th);
        aa.ca[i] = ca;
        aa.sa[i] = sa;
        aa.ox[i] = -1099.0f * (ca + sa - 1.0f);
        aa.oy[i] = -1099.0f * (ca - sa - 1.0f);
    }
    radon9<<<69 * 2 * NANG, 256, 0, stream>>>(padded, lines2, aa);
    reduce_max_k<<<(NLINE + 255) / 256, 256, 0, stream>>>(lines2, lines, gmax);
    norm_k<<<(NLINE + 255) / 256, 256, 0, stream>>>(lines, gmax, out);
}